// Round 8
// baseline (1103.632 us; speedup 1.0000x reference)
//
#include <hip/hip_runtime.h>
#include <cstdint>
#include <cstddef>

typedef unsigned short u16;
typedef __attribute__((ext_vector_type(8))) short s8v;   // 8 bf16 in 4 VGPRs
typedef __attribute__((ext_vector_type(4))) float f4v;   // MFMA accumulator
typedef __attribute__((ext_vector_type(2))) float f32x2;

#define D_MODEL 1024
#define D_INNER 2048
#define BT      8192   // B*T
#define TLEN    2048
#define NBATCH  4

struct alignas(8) U16x4 { u16 x, y, z, w; };

__device__ __forceinline__ u16 f2bf(float f) {
  union { float f; unsigned u; } c; c.f = f;
  unsigned r = c.u + 0x7FFFu + ((c.u >> 16) & 1u);   // RNE
  return (u16)(r >> 16);
}
// bf16 unpack from packed pair (u32): low ch / high ch
__device__ __forceinline__ float blo(unsigned u) {
  union { unsigned u; float f; } c; c.u = u << 16; return c.f;
}
__device__ __forceinline__ float bhi(unsigned u) {
  union { unsigned u; float f; } c; c.u = u & 0xffff0000u; return c.f;
}
// pack two fp32 -> packed bf16 pair (round half up), lo in low 16
__device__ __forceinline__ unsigned pkbf(float lo, float hi) {
  union { float f; unsigned u; } a, b; a.f = lo; b.f = hi;
#if __has_builtin(__builtin_amdgcn_perm)
  return __builtin_amdgcn_perm(b.u + 0x8000u, a.u + 0x8000u, 0x07060302u);
#else
  return ((b.u + 0x8000u) & 0xffff0000u) | ((a.u + 0x8000u) >> 16);
#endif
}

// DPP wave-64 sum: VALU-pipe latency instead of ds_bpermute. Result in lane 63.
#define DPPADD(x, ctrl) \
  ((x) + __builtin_bit_cast(float, __builtin_amdgcn_update_dpp( \
       0, __builtin_bit_cast(int, (x)), (ctrl), 0xF, 0xF, true)))
__device__ __forceinline__ float wave_sum_dpp(float x) {
  x = DPPADD(x, 0x111);  // row_shr:1
  x = DPPADD(x, 0x112);  // row_shr:2
  x = DPPADD(x, 0x114);  // row_shr:4
  x = DPPADD(x, 0x118);  // row_shr:8
  x = DPPADD(x, 0x142);  // row_bcast:15
  x = DPPADD(x, 0x143);  // row_bcast:31
  return x;              // lane 63 = wave sum
}

// async global->LDS, 16B per lane; LDS dest must be wave-uniform base (+lane*16 by HW)
__device__ __forceinline__ void glds16(const u16* g, const u16* lds) {
  __builtin_amdgcn_global_load_lds(
      (const __attribute__((address_space(1))) unsigned int*)(uintptr_t)g,
      (__attribute__((address_space(3))) unsigned int*)(unsigned int)(uintptr_t)lds,
      16, 0, 0);
}

// ---------------------------------------------------------------------------
// GEMM: 128x128 tile, now BK=64 (halves barrier count; 32 MFMA per barrier
// pair vs 16; LDS 32KB/block -> still 2 blocks/CU) + XCD swizzle (round-7
// verified). Staging: per wave 4 glds16/operand, each covering 8 rows x 64
// cols (lane = row*8 + colchunk, 16B per lane, LDS linear).
// EPI 0: Cb=xi bf16 | Cb2=silu(z) bf16 (N split at 2048)
// EPI 4: Cb2=bf16(1-lam)=bf16(-expm1(sfac*sigmoid(acc+bias))) | Cb=v bf16
// EPI 3: Cf = acc (fp32)
// ---------------------------------------------------------------------------
template<int EPI>
__global__ __launch_bounds__(256, 2)
void gemm_nt(const u16* __restrict__ A, const u16* __restrict__ B,
             int M, int N, int K,
             float* __restrict__ Cf, u16* __restrict__ Cb, u16* __restrict__ Cb2,
             const float* __restrict__ bias, const float* __restrict__ sfac,
             const float* __restrict__ bias2)
{
  __shared__ u16 lA[128 * 64];
  __shared__ u16 lB[128 * 64];
  const int tid  = threadIdx.x;
  const int wave = tid >> 6, lane = tid & 63;
  const int wm = wave >> 1, wn = wave & 1;

  // XCD swizzle on the flattened workgroup index (nwg % 8 == 0 for all uses)
  const int nwg = (int)(gridDim.x * gridDim.y);
  int wg = (int)(blockIdx.y * gridDim.x + blockIdx.x);
  wg = (wg & 7) * (nwg >> 3) + (wg >> 3);
  const int bm0 = (wg / (int)gridDim.x) * 128;
  const int bn0 = (wg % (int)gridDim.x) * 128;

  const int srow = lane >> 3;          // 0..7
  const int scol = (lane & 7) * 8;     // 0..56 (u16 units)
  const u16* pa = A + (size_t)(bm0 + wave * 32 + srow) * K + scol;
  const u16* pb = B + (size_t)(bn0 + wave * 32 + srow) * K + scol;
  u16* laB = lA + (wave * 32) * 64;
  u16* lbB = lB + (wave * 32) * 64;

  const int fr = lane & 15, kq = lane >> 4;
  const u16* fA = lA + (wm * 64 + fr) * 64 + kq * 8;
  const u16* fB = lB + (wn * 64 + fr) * 64 + kq * 8;

  f4v acc[4][4];
  const f4v zf = {0.f, 0.f, 0.f, 0.f};
  for (int i = 0; i < 4; ++i)
    for (int j = 0; j < 4; ++j)
      acc[i][j] = zf;

  for (int k0 = 0; k0 < K; k0 += 64) {
#pragma unroll
    for (int g = 0; g < 4; ++g) {
      glds16(pa + (size_t)(8 * g) * K + k0, laB + (8 * g) * 64);
      glds16(pb + (size_t)(8 * g) * K + k0, lbB + (8 * g) * 64);
    }
    __syncthreads();
#pragma unroll
    for (int ks = 0; ks < 2; ++ks) {
      s8v af[4], bfv[4];
#pragma unroll
      for (int i = 0; i < 4; ++i) af[i] = *(const s8v*)(fA + i * 16 * 64 + ks * 32);
#pragma unroll
      for (int j = 0; j < 4; ++j) bfv[j] = *(const s8v*)(fB + j * 16 * 64 + ks * 32);
#pragma unroll
      for (int i = 0; i < 4; ++i)
#pragma unroll
        for (int j = 0; j < 4; ++j)
          acc[i][j] = __builtin_amdgcn_mfma_f32_16x16x32_bf16(af[i], bfv[j], acc[i][j], 0, 0, 0);
    }
    __syncthreads();
  }

  // C/D layout: col = lane&15, row = (lane>>4)*4 + reg
#pragma unroll
  for (int i = 0; i < 4; ++i) {
#pragma unroll
    for (int j = 0; j < 4; ++j) {
#pragma unroll
      for (int r = 0; r < 4; ++r) {
        const int gm = bm0 + wm * 64 + i * 16 + kq * 4 + r;
        const int gn = bn0 + wn * 64 + j * 16 + fr;
        const float val = acc[i][j][r];
        if (EPI == 0) {
          if (gn < D_INNER) {
            Cb[(size_t)gm * D_INNER + gn] = f2bf(val);
          } else {
            const float s = val / (1.f + __expf(-val));  // silu(z)
            Cb2[(size_t)gm * D_INNER + (gn - D_INNER)] = f2bf(s);
          }
        } else if (EPI == 4) {
          if (gn < D_INNER) {
            const float pre = val + bias[gn];
            const float sig = 1.f / (1.f + __expf(-pre));
            const float m = -expm1f(sfac[gn] * sig);   // 1 - lam, full precision
            Cb2[(size_t)gm * D_INNER + gn] = f2bf(m);
          } else {
            Cb[(size_t)gm * D_INNER + (gn - D_INNER)] = f2bf(val + bias2[gn - D_INNER]);
          }
        } else {
          Cf[(size_t)gm * N + gn] = val;
        }
      }
    }
  }
}

// ---------------------------------------------------------------------------
// Fused bf16 conversion of all 5 inputs in ONE launch (outputs contiguous
// in the carve: [x | Win | Wl | Wv | Wout], float4 units).
// ---------------------------------------------------------------------------
#define CV_R0 2097152   // x end        (8192*1024/4)
#define CV_R1 3145728   // Win end      (+4096*1024/4)
#define CV_R2 4194304   // Wl end       (+2048*2048/4)
#define CV_R3 5242880   // Wv end
#define CV_R4 5767168   // Wout end     (+1024*2048/4)  == grid*256 exactly

__global__ __launch_bounds__(256)
void convall_kernel(const float* __restrict__ x, const float* __restrict__ Win,
                    const float* __restrict__ Wl, const float* __restrict__ Wv,
                    const float* __restrict__ Wout, u16* __restrict__ outb)
{
  const int g = blockIdx.x * 256 + threadIdx.x;   // float4 index, < CV_R4
  const float* in; int lo;
  if (g < CV_R0)      { in = x;    lo = g; }
  else if (g < CV_R1) { in = Win;  lo = g - CV_R0; }
  else if (g < CV_R2) { in = Wl;   lo = g - CV_R1; }
  else if (g < CV_R3) { in = Wv;   lo = g - CV_R2; }
  else                { in = Wout; lo = g - CV_R3; }
  const float4 v = ((const float4*)in)[lo];
  U16x4 o; o.x = f2bf(v.x); o.y = f2bf(v.y); o.z = f2bf(v.z); o.w = f2bf(v.w);
  ((U16x4*)outb)[g] = o;
}

__global__ void sfac_kernel(const float* __restrict__ omega, float* __restrict__ sfac)
{
  const int i = blockIdx.x * blockDim.x + threadIdx.x;
  if (i < D_INNER) sfac[i] = -8.f * log1pf(expf(omega[i]));  // -C*softplus(omega)
}

// ---------------------------------------------------------------------------
// Fused vscale + pairprep: one wave per even t handles rows (t, t+1):
//   1) norms of both raw v rows, sc = sqrt(2/(v.v))
//   2) scaled v rounded to bf16, written back (what the scan will read)
//   3) C1 = (v1 - v1*m0).v0, C2 = v1.(m0*x0) computed from the ROUNDED
//      scaled values -> identical bits to the old vscale->pairprep flow.
// Saves the separate vscale pass (134 MB traffic) + one launch.
// ---------------------------------------------------------------------------
__global__ __launch_bounds__(256)
void prep_kernel(u16* __restrict__ vs, const u16* __restrict__ mb,
                 const u16* __restrict__ xi, f32x2* __restrict__ C12)
{
  const int r = blockIdx.x * 4 + (threadIdx.x >> 6);  // r = b*1024 + t/2
  const int lane = threadIdx.x & 63;
  const int b = r >> 10;
  const int t = (r & 1023) * 2;
  const size_t o0 = ((size_t)b * TLEN + t) * D_INNER + (size_t)lane * 32;
  const size_t o1 = o0 + D_INNER;
  uint4* pv0 = (uint4*)(vs + o0);
  uint4* pv1 = (uint4*)(vs + o1);
  const uint4* px0 = (const uint4*)(xi + o0);
  const uint4* pm0 = (const uint4*)(mb + o0);

  uint4 a0[4], a1[4];
  float s0 = 0.f, s1 = 0.f;
#pragma unroll
  for (int i = 0; i < 4; ++i) {
    a0[i] = pv0[i]; a1[i] = pv1[i];
    const unsigned w0[4] = {a0[i].x, a0[i].y, a0[i].z, a0[i].w};
    const unsigned w1[4] = {a1[i].x, a1[i].y, a1[i].z, a1[i].w};
#pragma unroll
    for (int j = 0; j < 4; ++j) {
      const float f0 = blo(w0[j]), f1 = bhi(w0[j]);
      s0 += f0 * f0 + f1 * f1;
      const float g0 = blo(w1[j]), g1 = bhi(w1[j]);
      s1 += g0 * g0 + g1 * g1;
    }
  }
  s0 += __shfl_down(s0, 32); s0 += __shfl_down(s0, 16); s0 += __shfl_down(s0, 8);
  s0 += __shfl_down(s0, 4);  s0 += __shfl_down(s0, 2);  s0 += __shfl_down(s0, 1);
  s1 += __shfl_down(s1, 32); s1 += __shfl_down(s1, 16); s1 += __shfl_down(s1, 8);
  s1 += __shfl_down(s1, 4);  s1 += __shfl_down(s1, 2);  s1 += __shfl_down(s1, 1);
  const float sc0 = sqrtf(2.f / __shfl(s0, 0));
  const float sc1 = sqrtf(2.f / __shfl(s1, 0));

  float c1 = 0.f, c2 = 0.f;
#pragma unroll
  for (int i = 0; i < 4; ++i) {
    const unsigned w0[4] = {a0[i].x, a0[i].y, a0[i].z, a0[i].w};
    const unsigned w1[4] = {a1[i].x, a1[i].y, a1[i].z, a1[i].w};
    unsigned ow0[4], ow1[4];
#pragma unroll
    for (int j = 0; j < 4; ++j) {
      ow0[j] = pkbf(blo(w0[j]) * sc0, bhi(w0[j]) * sc0);
      ow1[j] = pkbf(blo(w1[j]) * sc1, bhi(w1[j]) * sc1);
    }
    uint4 v0o; v0o.x = ow0[0]; v0o.y = ow0[1]; v0o.z = ow0[2]; v0o.w = ow0[3];
    uint4 v1o; v1o.x = ow1[0]; v1o.y = ow1[1]; v1o.z = ow1[2]; v1o.w = ow1[3];
    pv0[i] = v0o;
    pv1[i] = v1o;
    const uint4 m0 = pm0[i], x0 = px0[i];
    const unsigned m0w[4] = {m0.x, m0.y, m0.z, m0.w};
    const unsigned x0w[4] = {x0.x, x0.y, x0.z, x0.w};
#pragma unroll
    for (int q = 0; q < 4; ++q) {
      const float va = blo(ow0[q]), vb = bhi(ow0[q]);   // rounded scaled v0
      const float ua = blo(ow1[q]), ub = bhi(ow1[q]);   // rounded scaled v1
      const float xa = blo(x0w[q]), xb = bhi(x0w[q]);
      const float ma = blo(m0w[q]), mbv = bhi(m0w[q]);
      const float wa = __builtin_fmaf(-ua, ma, ua);     // v1*(1-m0), fp32
      const float wb = __builtin_fmaf(-ub, mbv, ub);
      c1 += wa * va + wb * vb;
      c2 += ua * (ma * xa) + ub * (mbv * xb);
    }
  }
  c1 = wave_sum_dpp(c1);
  c2 = wave_sum_dpp(c2);
  if (lane == 63) { f32x2 cc; cc.x = c1; cc.y = c2; C12[r] = cc; }
}

// gh <- sz * gh  elementwise (full chip), in-place over the h buffer
__global__ void zmul_kernel(u16* __restrict__ gh, const u16* __restrict__ sz, int n8)
{
  const int i = blockIdx.x * blockDim.x + threadIdx.x;
  if (i >= n8) return;
  const uint4 hv = ((const uint4*)gh)[i];
  const uint4 zv = ((const uint4*)sz)[i];
  const unsigned hw[4] = {hv.x, hv.y, hv.z, hv.w};
  const unsigned zw[4] = {zv.x, zv.y, zv.z, zv.w};
  unsigned ow[4];
#pragma unroll
  for (int q = 0; q < 4; ++q)
    ow[q] = pkbf(blo(zw[q]) * blo(hw[q]), bhi(zw[q]) * bhi(hw[q]));
  uint4 o; o.x = ow[0]; o.y = ow[1]; o.z = ow[2]; o.w = ow[3];
  ((uint4*)gh)[i] = o;
}

// ---------------------------------------------------------------------------
// Paired sequential scan — round-4 verified body, prefetch depth 3 (three
// Pair buffers, same separate-struct + sched_barrier pattern). If the scan
// is CU-fill-rate-bound this is null; if latency-edged, -20-40us.
// ---------------------------------------------------------------------------
struct Pair {
  uint4 v0, v1, x0, x1, m0, m1;
  f32x2 c;
};

__global__ __launch_bounds__(256, 1)
void scan2_kernel(const u16* __restrict__ xi, const u16* __restrict__ vs,
                  const u16* __restrict__ mb, const f32x2* __restrict__ C12,
                  u16* __restrict__ hb)
{
  const int b = blockIdx.x, tid = threadIdx.x;
  const int wave = tid >> 6, lane = tid & 63;
  const size_t base = (size_t)b * TLEN * D_INNER + (size_t)tid * 8;
  const int cb0 = b * 1024;
  __shared__ __attribute__((aligned(16))) float rP[2][4], rQ[2][4];

  auto load_pair = [&](int t) {
    Pair p;
    const size_t o0 = base + (size_t)t * D_INNER;
    const size_t o1 = o0 + D_INNER;
    p.v0 = *(const uint4*)(vs + o0);
    p.v1 = *(const uint4*)(vs + o1);
    p.x0 = *(const uint4*)(xi + o0);
    p.x1 = *(const uint4*)(xi + o1);
    p.m0 = *(const uint4*)(mb + o0);
    p.m1 = *(const uint4*)(mb + o1);
    p.c = C12[cb0 + (t >> 1)];
    return p;
  };

  float h[8];
  {  // t = 0: h = xi (exact bf16 copy)
    const uint4 x0 = *(const uint4*)(xi + base);
    const unsigned xw[4] = {x0.x, x0.y, x0.z, x0.w};
#pragma unroll
    for (int p = 0; p < 4; ++p) {
      h[2*p]   = blo(xw[p]);
      h[2*p+1] = bhi(xw[p]);
    }
    *(uint4*)(hb + base) = x0;
  }

  {  // solo step t = 1
    const size_t o = base + D_INNER;
    const uint4 v1v = *(const uint4*)(vs + o);
    const uint4 x1v = *(const uint4*)(xi + o);
    const uint4 m1v = *(const uint4*)(mb + o);
    const unsigned vw[4] = {v1v.x, v1v.y, v1v.z, v1v.w};
    float vf[8];
    float P0 = 0.f, P1 = 0.f;
#pragma unroll
    for (int p = 0; p < 4; ++p) {
      vf[2*p]   = blo(vw[p]);
      vf[2*p+1] = bhi(vw[p]);
      P0 = __builtin_fmaf(vf[2*p],   h[2*p],   P0);
      P1 = __builtin_fmaf(vf[2*p+1], h[2*p+1], P1);
    }
    float P = wave_sum_dpp(P0 + P1);
    if (lane == 63) rP[0][wave] = P;
    asm volatile("s_waitcnt lgkmcnt(0)\n\ts_barrier" ::: "memory");
    const float4 sp = *(const float4*)rP[0];
    const float a = (sp.x + sp.y) + (sp.z + sp.w);
    const unsigned xw[4] = {x1v.x, x1v.y, x1v.z, x1v.w};
    const unsigned mw[4] = {m1v.x, m1v.y, m1v.z, m1v.w};
    unsigned ow[4];
#pragma unroll
    for (int p = 0; p < 4; ++p) {
      const float X0 = blo(xw[p]), X1 = bhi(xw[p]);
      const float M0 = blo(mw[p]), M1 = bhi(mw[p]);
      const float t0 = __builtin_fmaf(vf[2*p],   -a, h[2*p]);
      const float t1 = __builtin_fmaf(vf[2*p+1], -a, h[2*p+1]);
      h[2*p]   = __builtin_fmaf(M0, X0 - t0, t0);
      h[2*p+1] = __builtin_fmaf(M1, X1 - t1, t1);
      ow[p] = pkbf(h[2*p], h[2*p+1]);
    }
    uint4 out; out.x = ow[0]; out.y = ow[1]; out.z = ow[2]; out.w = ow[3];
    *(uint4*)(hb + o) = out;
  }

  auto round = [&](const Pair& p, int t) {
    const int par = (t >> 1) & 1;
    const unsigned v0w[4] = {p.v0.x, p.v0.y, p.v0.z, p.v0.w};
    const unsigned v1w[4] = {p.v1.x, p.v1.y, p.v1.z, p.v1.w};
    const unsigned m0w[4] = {p.m0.x, p.m0.y, p.m0.z, p.m0.w};
    float vf[8], uf[8], mf0[8];
    float P0 = 0.f, P1 = 0.f, Q0 = 0.f, Q1 = 0.f;
#pragma unroll
    for (int q = 0; q < 4; ++q) {
      vf[2*q]   = blo(v0w[q]);
      vf[2*q+1] = bhi(v0w[q]);
      uf[2*q]   = blo(v1w[q]);
      uf[2*q+1] = bhi(v1w[q]);
      mf0[2*q]  = blo(m0w[q]);
      mf0[2*q+1]= bhi(m0w[q]);
      const float wa = __builtin_fmaf(-uf[2*q],   mf0[2*q],   uf[2*q]);   // v1*l0
      const float wb = __builtin_fmaf(-uf[2*q+1], mf0[2*q+1], uf[2*q+1]);
      P0 = __builtin_fmaf(vf[2*q],   h[2*q],   P0);
      P1 = __builtin_fmaf(vf[2*q+1], h[2*q+1], P1);
      Q0 = __builtin_fmaf(wa, h[2*q],   Q0);
      Q1 = __builtin_fmaf(wb, h[2*q+1], Q1);
    }
    float P = wave_sum_dpp(P0 + P1);
    float Q = wave_sum_dpp(Q0 + Q1);
    if (lane == 63) { rP[par][wave] = P; rQ[par][wave] = Q; }
    asm volatile("s_waitcnt lgkmcnt(0)\n\ts_barrier" ::: "memory");
    const float4 sp = *(const float4*)rP[par];
    const float4 sq = *(const float4*)rQ[par];
    const float a0 = (sp.x + sp.y) + (sp.z + sp.w);
    const float a1 = __builtin_fmaf(-a0, p.c.x, (sq.x + sq.y) + (sq.z + sq.w) + p.c.y);
    const unsigned xw0[4] = {p.x0.x, p.x0.y, p.x0.z, p.x0.w};
    const unsigned xw1[4] = {p.x1.x, p.x1.y, p.x1.z, p.x1.w};
    const unsigned m1w[4] = {p.m1.x, p.m1.y, p.m1.z, p.m1.w};
    unsigned ow0[4], ow1[4];
#pragma unroll
    for (int q = 0; q < 4; ++q) {
      const float A0 = blo(xw0[q]), A1 = bhi(xw0[q]);
      const float B0 = blo(xw1[q]), B1 = bhi(xw1[q]);
      const float N0 = blo(m1w[q]), N1 = bhi(m1w[q]);
      float t0 = __builtin_fmaf(vf[2*q],   -a0, h[2*q]);
      float t1 = __builtin_fmaf(vf[2*q+1], -a0, h[2*q+1]);
      t0 = __builtin_fmaf(mf0[2*q],   A0 - t0, t0);   // h_t
      t1 = __builtin_fmaf(mf0[2*q+1], A1 - t1, t1);
      ow0[q] = pkbf(t0, t1);
      const float u0 = __builtin_fmaf(uf[2*q],   -a1, t0);
      const float u1 = __builtin_fmaf(uf[2*q+1], -a1, t1);
      h[2*q]   = __builtin_fmaf(N0, B0 - u0, u0);     // h_{t+1}
      h[2*q+1] = __builtin_fmaf(N1, B1 - u1, u1);
      ow1[q] = pkbf(h[2*q], h[2*q+1]);
    }
    const size_t oo = base + (size_t)t * D_INNER;
    uint4 o0; o0.x = ow0[0]; o0.y = ow0[1]; o0.z = ow0[2]; o0.w = ow0[3];
    uint4 o1; o1.x = ow1[0]; o1.y = ow1[1]; o1.z = ow1[2]; o1.w = ow1[3];
    *(uint4*)(hb + oo) = o0;
    *(uint4*)(hb + oo + D_INNER) = o1;
  };

  // Software pipeline, depth = 3 rounds; sched_barrier(0) pins load clumps.
  // 1023 rounds = 340 iters x 3 (t=2..2040) + 3 epilogue (2042,2044,2046).
  Pair A = load_pair(2);
  __builtin_amdgcn_sched_barrier(0);
  Pair B = load_pair(4);
  __builtin_amdgcn_sched_barrier(0);
  Pair C = load_pair(6);
  __builtin_amdgcn_sched_barrier(0);
  for (int t = 2; t <= 2036; t += 6) {
    Pair An = load_pair(t + 6);
    __builtin_amdgcn_sched_barrier(0);
    round(A, t);
    A = An;
    Pair Bn = load_pair(t + 8);
    __builtin_amdgcn_sched_barrier(0);
    round(B, t + 2);
    B = Bn;
    Pair Cn = load_pair(t + 10);
    __builtin_amdgcn_sched_barrier(0);
    round(C, t + 4);
    C = Cn;
  }
  round(A, 2042);
  round(B, 2044);
  round(C, 2046);
}

extern "C" void kernel_launch(void* const* d_in, const int* in_sizes, int n_in,
                              void* d_out, int out_size, void* d_ws, size_t ws_size,
                              hipStream_t stream)
{
  const float* x     = (const float*)d_in[0];
  const float* omega = (const float*)d_in[1];
  const float* Win   = (const float*)d_in[2];
  const float* Wl    = (const float*)d_in[3];
  const float* bl    = (const float*)d_in[4];
  const float* Wv    = (const float*)d_in[5];
  const float* bv    = (const float*)d_in[6];
  const float* Wout  = (const float*)d_in[7];
  float* out = (float*)d_out;
  (void)in_sizes; (void)n_in; (void)out_size; (void)ws_size;

  size_t off = 0;
  auto carve = [&](size_t bytes) -> void* {
    void* r = (char*)d_ws + off;
    off += (bytes + 255) & ~(size_t)255;
    return r;
  };
  u16*  x_bf    = (u16*)carve((size_t)BT * D_MODEL * 2);          // conv region base
  u16*  Win_bf  = (u16*)carve((size_t)2 * D_INNER * D_MODEL * 2);
  u16*  Wl_bf   = (u16*)carve((size_t)D_INNER * D_INNER * 2);
  u16*  Wv_bf   = (u16*)carve((size_t)D_INNER * D_INNER * 2);
  u16*  Wout_bf = (u16*)carve((size_t)D_MODEL * D_INNER * 2);
  u16*  xi_bf   = (u16*)carve((size_t)BT * D_INNER * 2);
  u16*  sz_bf   = (u16*)carve((size_t)BT * D_INNER * 2);
  u16*  v_bf    = (u16*)carve((size_t)BT * D_INNER * 2);
  u16*  gh_bf   = (u16*)carve((size_t)BT * D_INNER * 2);   // scan h, then z*h in-place
  u16*  mb      = (u16*)carve((size_t)BT * D_INNER * 2);   // 1-lam, bf16
  float* sfac   = (float*)carve((size_t)D_INNER * 4);
  f32x2* C12    = (f32x2*)carve((size_t)(BT / 2) * 8);

  // all 5 input conversions in one launch (outputs contiguous from x_bf)
  convall_kernel<<<CV_R4 / 256, 256, 0, stream>>>(x, Win, Wl, Wv, Wout, x_bf);
  sfac_kernel<<<(D_INNER + 255) / 256, 256, 0, stream>>>(omega, sfac);

  // xz = x @ Win^T  -> xi (bf16) | silu(z) (bf16)
  gemm_nt<0><<<dim3(4096 / 128, BT / 128), 256, 0, stream>>>(
      x_bf, Win_bf, BT, 4096, D_MODEL, nullptr, xi_bf, sz_bf, nullptr, nullptr, nullptr);
  // merged: mb = bf16(1-lam) | v = xi@Wv^T+bv bf16
  gemm_nt<4><<<dim3(4096 / 128, BT / 128), 256, 0, stream>>>(
      xi_bf, Wl_bf, BT, 4096, D_INNER, nullptr, v_bf, mb, bl, sfac, bv);
  // fused: v <- v*sqrt(2/(v.v)) (rounded) + C12 from rounded values
  prep_kernel<<<BT / 2 / 4, 256, 0, stream>>>(v_bf, mb, xi_bf, C12);
  // paired sequential scan (depth-3 prefetch) -> hb = h (bf16)
  scan2_kernel<<<NBATCH, 256, 0, stream>>>(xi_bf, v_bf, mb, C12, gh_bf);
  // gh = silu(z)*h (full chip, in-place)
  zmul_kernel<<<(BT * D_INNER / 8 + 255) / 256, 256, 0, stream>>>(gh_bf, sz_bf, BT * D_INNER / 8);
  // out = gh @ Wout^T (fp32)
  gemm_nt<3><<<dim3(D_MODEL / 128, BT / 128), 256, 0, stream>>>(
      gh_bf, Wout_bf, BT, D_MODEL, D_INNER, out, nullptr, nullptr, nullptr, nullptr, nullptr);
}

// Round 9
// 1055.972 us; speedup vs baseline: 1.0451x; 1.0451x over previous
//
#include <hip/hip_runtime.h>
#include <cstdint>
#include <cstddef>

typedef unsigned short u16;
typedef __attribute__((ext_vector_type(8))) short s8v;   // 8 bf16 in 4 VGPRs
typedef __attribute__((ext_vector_type(4))) float f4v;   // MFMA accumulator
typedef __attribute__((ext_vector_type(2))) float f32x2;

#define D_MODEL 1024
#define D_INNER 2048
#define BT      8192   // B*T
#define TLEN    2048
#define NBATCH  4

struct alignas(8) U16x4 { u16 x, y, z, w; };

__device__ __forceinline__ u16 f2bf(float f) {
  union { float f; unsigned u; } c; c.f = f;
  unsigned r = c.u + 0x7FFFu + ((c.u >> 16) & 1u);   // RNE
  return (u16)(r >> 16);
}
// bf16 unpack from packed pair (u32): low ch / high ch
__device__ __forceinline__ float blo(unsigned u) {
  union { unsigned u; float f; } c; c.u = u << 16; return c.f;
}
__device__ __forceinline__ float bhi(unsigned u) {
  union { unsigned u; float f; } c; c.u = u & 0xffff0000u; return c.f;
}
// pack two fp32 -> packed bf16 pair (round half up), lo in low 16
__device__ __forceinline__ unsigned pkbf(float lo, float hi) {
  union { float f; unsigned u; } a, b; a.f = lo; b.f = hi;
#if __has_builtin(__builtin_amdgcn_perm)
  return __builtin_amdgcn_perm(b.u + 0x8000u, a.u + 0x8000u, 0x07060302u);
#else
  return ((b.u + 0x8000u) & 0xffff0000u) | ((a.u + 0x8000u) >> 16);
#endif
}

// DPP wave-64 sum: VALU-pipe latency instead of ds_bpermute. Result in lane 63.
#define DPPADD(x, ctrl) \
  ((x) + __builtin_bit_cast(float, __builtin_amdgcn_update_dpp( \
       0, __builtin_bit_cast(int, (x)), (ctrl), 0xF, 0xF, true)))
__device__ __forceinline__ float wave_sum_dpp(float x) {
  x = DPPADD(x, 0x111);  // row_shr:1
  x = DPPADD(x, 0x112);  // row_shr:2
  x = DPPADD(x, 0x114);  // row_shr:4
  x = DPPADD(x, 0x118);  // row_shr:8
  x = DPPADD(x, 0x142);  // row_bcast:15
  x = DPPADD(x, 0x143);  // row_bcast:31
  return x;              // lane 63 = wave sum
}

// async global->LDS, 16B per lane; LDS dest must be wave-uniform base (+lane*16 by HW)
__device__ __forceinline__ void glds16(const u16* g, const u16* lds) {
  __builtin_amdgcn_global_load_lds(
      (const __attribute__((address_space(1))) unsigned int*)(uintptr_t)g,
      (__attribute__((address_space(3))) unsigned int*)(unsigned int)(uintptr_t)lds,
      16, 0, 0);
}

// ---------------------------------------------------------------------------
// GEMM: round-7 verified structure (BK=32, 128x128 tile, XCD swizzle), with
// __launch_bounds__(256,3): the (256,2) bound capped residency at 2 blocks/CU;
// 3 blocks/CU (VGPR cap ~168, kernel needs ~130; LDS 16KB x3 = 48KB of 160)
// lets other blocks' MFMA fill this block's barrier-drain stall (the known
// ~20% of this structure).
// EPI 0: Cb=xi bf16 | Cb2=silu(z) bf16 (N split at 2048)
// EPI 4: Cb2=bf16(1-lam)=bf16(-expm1(sfac*sigmoid(acc+bias))) | Cb=v bf16
// EPI 3: Cf = acc (fp32)
// ---------------------------------------------------------------------------
template<int EPI>
__global__ __launch_bounds__(256, 3)
void gemm_nt(const u16* __restrict__ A, const u16* __restrict__ B,
             int M, int N, int K,
             float* __restrict__ Cf, u16* __restrict__ Cb, u16* __restrict__ Cb2,
             const float* __restrict__ bias, const float* __restrict__ sfac,
             const float* __restrict__ bias2)
{
  __shared__ u16 lA[128 * 32];
  __shared__ u16 lB[128 * 32];
  const int tid  = threadIdx.x;
  const int wave = tid >> 6, lane = tid & 63;
  const int wm = wave >> 1, wn = wave & 1;

  // XCD swizzle on the flattened workgroup index (nwg % 8 == 0 for all uses)
  const int nwg = (int)(gridDim.x * gridDim.y);
  int wg = (int)(blockIdx.y * gridDim.x + blockIdx.x);
  wg = (wg & 7) * (nwg >> 3) + (wg >> 3);
  const int bm0 = (wg / (int)gridDim.x) * 128;
  const int bn0 = (wg % (int)gridDim.x) * 128;

  const int srow = lane >> 2;
  const int scol = (lane & 3) * 8;
  const u16* pa0 = A + (size_t)(bm0 + wave * 32 + srow) * K + scol;
  const u16* pa1 = pa0 + (size_t)16 * K;
  const u16* pb0 = B + (size_t)(bn0 + wave * 32 + srow) * K + scol;
  const u16* pb1 = pb0 + (size_t)16 * K;
  u16* la0 = lA + (wave * 32) * 32;
  u16* la1 = la0 + 16 * 32;
  u16* lb0 = lB + (wave * 32) * 32;
  u16* lb1 = lb0 + 16 * 32;

  const int fr = lane & 15, kq = lane >> 4;
  const u16* fA = lA + (wm * 64 + fr) * 32 + kq * 8;
  const u16* fB = lB + (wn * 64 + fr) * 32 + kq * 8;

  f4v acc[4][4];
  const f4v zf = {0.f, 0.f, 0.f, 0.f};
  for (int i = 0; i < 4; ++i)
    for (int j = 0; j < 4; ++j)
      acc[i][j] = zf;

  for (int k0 = 0; k0 < K; k0 += 32) {
    glds16(pa0 + k0, la0);
    glds16(pa1 + k0, la1);
    glds16(pb0 + k0, lb0);
    glds16(pb1 + k0, lb1);
    __syncthreads();
    s8v af[4], bfv[4];
#pragma unroll
    for (int i = 0; i < 4; ++i) af[i] = *(const s8v*)(fA + i * 16 * 32);
#pragma unroll
    for (int j = 0; j < 4; ++j) bfv[j] = *(const s8v*)(fB + j * 16 * 32);
#pragma unroll
    for (int i = 0; i < 4; ++i)
#pragma unroll
      for (int j = 0; j < 4; ++j)
        acc[i][j] = __builtin_amdgcn_mfma_f32_16x16x32_bf16(af[i], bfv[j], acc[i][j], 0, 0, 0);
    __syncthreads();
  }

  // C/D layout: col = lane&15, row = (lane>>4)*4 + reg
#pragma unroll
  for (int i = 0; i < 4; ++i) {
#pragma unroll
    for (int j = 0; j < 4; ++j) {
#pragma unroll
      for (int r = 0; r < 4; ++r) {
        const int gm = bm0 + wm * 64 + i * 16 + kq * 4 + r;
        const int gn = bn0 + wn * 64 + j * 16 + fr;
        const float val = acc[i][j][r];
        if (EPI == 0) {
          if (gn < D_INNER) {
            Cb[(size_t)gm * D_INNER + gn] = f2bf(val);
          } else {
            const float s = val / (1.f + __expf(-val));  // silu(z)
            Cb2[(size_t)gm * D_INNER + (gn - D_INNER)] = f2bf(s);
          }
        } else if (EPI == 4) {
          if (gn < D_INNER) {
            const float pre = val + bias[gn];
            const float sig = 1.f / (1.f + __expf(-pre));
            const float m = -expm1f(sfac[gn] * sig);   // 1 - lam, full precision
            Cb2[(size_t)gm * D_INNER + gn] = f2bf(m);
          } else {
            Cb[(size_t)gm * D_INNER + (gn - D_INNER)] = f2bf(val + bias2[gn - D_INNER]);
          }
        } else {
          Cf[(size_t)gm * N + gn] = val;
        }
      }
    }
  }
}

// ---------------------------------------------------------------------------
// Fused bf16 conversion of all 5 inputs in ONE launch (outputs contiguous
// in the carve: [x | Win | Wl | Wv | Wout], float4 units).
// ---------------------------------------------------------------------------
#define CV_R0 2097152   // x end        (8192*1024/4)
#define CV_R1 3145728   // Win end      (+4096*1024/4)
#define CV_R2 4194304   // Wl end       (+2048*2048/4)
#define CV_R3 5242880   // Wv end
#define CV_R4 5767168   // Wout end     (+1024*2048/4)  == grid*256 exactly

__global__ __launch_bounds__(256)
void convall_kernel(const float* __restrict__ x, const float* __restrict__ Win,
                    const float* __restrict__ Wl, const float* __restrict__ Wv,
                    const float* __restrict__ Wout, u16* __restrict__ outb)
{
  const int g = blockIdx.x * 256 + threadIdx.x;   // float4 index, < CV_R4
  const float* in; int lo;
  if (g < CV_R0)      { in = x;    lo = g; }
  else if (g < CV_R1) { in = Win;  lo = g - CV_R0; }
  else if (g < CV_R2) { in = Wl;   lo = g - CV_R1; }
  else if (g < CV_R3) { in = Wv;   lo = g - CV_R2; }
  else                { in = Wout; lo = g - CV_R3; }
  const float4 v = ((const float4*)in)[lo];
  U16x4 o; o.x = f2bf(v.x); o.y = f2bf(v.y); o.z = f2bf(v.z); o.w = f2bf(v.w);
  ((U16x4*)outb)[g] = o;
}

__global__ void sfac_kernel(const float* __restrict__ omega, float* __restrict__ sfac)
{
  const int i = blockIdx.x * blockDim.x + threadIdx.x;
  if (i < D_INNER) sfac[i] = -8.f * log1pf(expf(omega[i]));  // -C*softplus(omega)
}

// ---------------------------------------------------------------------------
// Fused vscale + pairprep (round-8 verified, absmax unchanged): one wave per
// even t handles rows (t, t+1): row norms -> scaled v rounded to bf16,
// written back; C1/C2 computed from the ROUNDED values (identical bits to
// what the scan reads). Saves the separate vscale pass (134 MB) + 1 launch.
// ---------------------------------------------------------------------------
__global__ __launch_bounds__(256)
void prep_kernel(u16* __restrict__ vs, const u16* __restrict__ mb,
                 const u16* __restrict__ xi, f32x2* __restrict__ C12)
{
  const int r = blockIdx.x * 4 + (threadIdx.x >> 6);  // r = b*1024 + t/2
  const int lane = threadIdx.x & 63;
  const int b = r >> 10;
  const int t = (r & 1023) * 2;
  const size_t o0 = ((size_t)b * TLEN + t) * D_INNER + (size_t)lane * 32;
  const size_t o1 = o0 + D_INNER;
  uint4* pv0 = (uint4*)(vs + o0);
  uint4* pv1 = (uint4*)(vs + o1);
  const uint4* px0 = (const uint4*)(xi + o0);
  const uint4* pm0 = (const uint4*)(mb + o0);

  uint4 a0[4], a1[4];
  float s0 = 0.f, s1 = 0.f;
#pragma unroll
  for (int i = 0; i < 4; ++i) {
    a0[i] = pv0[i]; a1[i] = pv1[i];
    const unsigned w0[4] = {a0[i].x, a0[i].y, a0[i].z, a0[i].w};
    const unsigned w1[4] = {a1[i].x, a1[i].y, a1[i].z, a1[i].w};
#pragma unroll
    for (int j = 0; j < 4; ++j) {
      const float f0 = blo(w0[j]), f1 = bhi(w0[j]);
      s0 += f0 * f0 + f1 * f1;
      const float g0 = blo(w1[j]), g1 = bhi(w1[j]);
      s1 += g0 * g0 + g1 * g1;
    }
  }
  s0 += __shfl_down(s0, 32); s0 += __shfl_down(s0, 16); s0 += __shfl_down(s0, 8);
  s0 += __shfl_down(s0, 4);  s0 += __shfl_down(s0, 2);  s0 += __shfl_down(s0, 1);
  s1 += __shfl_down(s1, 32); s1 += __shfl_down(s1, 16); s1 += __shfl_down(s1, 8);
  s1 += __shfl_down(s1, 4);  s1 += __shfl_down(s1, 2);  s1 += __shfl_down(s1, 1);
  const float sc0 = sqrtf(2.f / __shfl(s0, 0));
  const float sc1 = sqrtf(2.f / __shfl(s1, 0));

  float c1 = 0.f, c2 = 0.f;
#pragma unroll
  for (int i = 0; i < 4; ++i) {
    const unsigned w0[4] = {a0[i].x, a0[i].y, a0[i].z, a0[i].w};
    const unsigned w1[4] = {a1[i].x, a1[i].y, a1[i].z, a1[i].w};
    unsigned ow0[4], ow1[4];
#pragma unroll
    for (int j = 0; j < 4; ++j) {
      ow0[j] = pkbf(blo(w0[j]) * sc0, bhi(w0[j]) * sc0);
      ow1[j] = pkbf(blo(w1[j]) * sc1, bhi(w1[j]) * sc1);
    }
    uint4 v0o; v0o.x = ow0[0]; v0o.y = ow0[1]; v0o.z = ow0[2]; v0o.w = ow0[3];
    uint4 v1o; v1o.x = ow1[0]; v1o.y = ow1[1]; v1o.z = ow1[2]; v1o.w = ow1[3];
    pv0[i] = v0o;
    pv1[i] = v1o;
    const uint4 m0 = pm0[i], x0 = px0[i];
    const unsigned m0w[4] = {m0.x, m0.y, m0.z, m0.w};
    const unsigned x0w[4] = {x0.x, x0.y, x0.z, x0.w};
#pragma unroll
    for (int q = 0; q < 4; ++q) {
      const float va = blo(ow0[q]), vb = bhi(ow0[q]);   // rounded scaled v0
      const float ua = blo(ow1[q]), ub = bhi(ow1[q]);   // rounded scaled v1
      const float xa = blo(x0w[q]), xb = bhi(x0w[q]);
      const float ma = blo(m0w[q]), mbv = bhi(m0w[q]);
      const float wa = __builtin_fmaf(-ua, ma, ua);     // v1*(1-m0), fp32
      const float wb = __builtin_fmaf(-ub, mbv, ub);
      c1 += wa * va + wb * vb;
      c2 += ua * (ma * xa) + ub * (mbv * xb);
    }
  }
  c1 = wave_sum_dpp(c1);
  c2 = wave_sum_dpp(c2);
  if (lane == 63) { f32x2 cc; cc.x = c1; cc.y = c2; C12[r] = cc; }
}

// gh <- sz * gh  elementwise (full chip), in-place over the h buffer
__global__ void zmul_kernel(u16* __restrict__ gh, const u16* __restrict__ sz, int n8)
{
  const int i = blockIdx.x * blockDim.x + threadIdx.x;
  if (i >= n8) return;
  const uint4 hv = ((const uint4*)gh)[i];
  const uint4 zv = ((const uint4*)sz)[i];
  const unsigned hw[4] = {hv.x, hv.y, hv.z, hv.w};
  const unsigned zw[4] = {zv.x, zv.y, zv.z, zv.w};
  unsigned ow[4];
#pragma unroll
  for (int q = 0; q < 4; ++q)
    ow[q] = pkbf(blo(zw[q]) * blo(hw[q]), bhi(zw[q]) * bhi(hw[q]));
  uint4 o; o.x = ow[0]; o.y = ow[1]; o.z = ow[2]; o.w = ow[3];
  ((uint4*)gh)[i] = o;
}

// ---------------------------------------------------------------------------
// Paired sequential scan — EXACT round-4/7 verified version (577 us, VGPR 76):
// 256 thr, 8 ch/thread, uint4 loads, depth-2 separate-struct prefetch +
// sched_barrier pins, plain stores. Variants tested and rejected: G=4 (927),
// G=8 (695), 512-thr (667), depth-3 (586).
// ---------------------------------------------------------------------------
struct Pair {
  uint4 v0, v1, x0, x1, m0, m1;
  f32x2 c;
};

__global__ __launch_bounds__(256, 1)
void scan2_kernel(const u16* __restrict__ xi, const u16* __restrict__ vs,
                  const u16* __restrict__ mb, const f32x2* __restrict__ C12,
                  u16* __restrict__ hb)
{
  const int b = blockIdx.x, tid = threadIdx.x;
  const int wave = tid >> 6, lane = tid & 63;
  const size_t base = (size_t)b * TLEN * D_INNER + (size_t)tid * 8;
  const int cb0 = b * 1024;
  __shared__ __attribute__((aligned(16))) float rP[2][4], rQ[2][4];

  auto load_pair = [&](int t) {
    Pair p;
    const size_t o0 = base + (size_t)t * D_INNER;
    const size_t o1 = o0 + D_INNER;
    p.v0 = *(const uint4*)(vs + o0);
    p.v1 = *(const uint4*)(vs + o1);
    p.x0 = *(const uint4*)(xi + o0);
    p.x1 = *(const uint4*)(xi + o1);
    p.m0 = *(const uint4*)(mb + o0);
    p.m1 = *(const uint4*)(mb + o1);
    p.c = C12[cb0 + (t >> 1)];
    return p;
  };

  float h[8];
  {  // t = 0: h = xi (exact bf16 copy)
    const uint4 x0 = *(const uint4*)(xi + base);
    const unsigned xw[4] = {x0.x, x0.y, x0.z, x0.w};
#pragma unroll
    for (int p = 0; p < 4; ++p) {
      h[2*p]   = blo(xw[p]);
      h[2*p+1] = bhi(xw[p]);
    }
    *(uint4*)(hb + base) = x0;
  }

  {  // solo step t = 1
    const size_t o = base + D_INNER;
    const uint4 v1v = *(const uint4*)(vs + o);
    const uint4 x1v = *(const uint4*)(xi + o);
    const uint4 m1v = *(const uint4*)(mb + o);
    const unsigned vw[4] = {v1v.x, v1v.y, v1v.z, v1v.w};
    float vf[8];
    float P0 = 0.f, P1 = 0.f;
#pragma unroll
    for (int p = 0; p < 4; ++p) {
      vf[2*p]   = blo(vw[p]);
      vf[2*p+1] = bhi(vw[p]);
      P0 = __builtin_fmaf(vf[2*p],   h[2*p],   P0);
      P1 = __builtin_fmaf(vf[2*p+1], h[2*p+1], P1);
    }
    float P = wave_sum_dpp(P0 + P1);
    if (lane == 63) rP[0][wave] = P;
    asm volatile("s_waitcnt lgkmcnt(0)\n\ts_barrier" ::: "memory");
    const float4 sp = *(const float4*)rP[0];
    const float a = (sp.x + sp.y) + (sp.z + sp.w);
    const unsigned xw[4] = {x1v.x, x1v.y, x1v.z, x1v.w};
    const unsigned mw[4] = {m1v.x, m1v.y, m1v.z, m1v.w};
    unsigned ow[4];
#pragma unroll
    for (int p = 0; p < 4; ++p) {
      const float X0 = blo(xw[p]), X1 = bhi(xw[p]);
      const float M0 = blo(mw[p]), M1 = bhi(mw[p]);
      const float t0 = __builtin_fmaf(vf[2*p],   -a, h[2*p]);
      const float t1 = __builtin_fmaf(vf[2*p+1], -a, h[2*p+1]);
      h[2*p]   = __builtin_fmaf(M0, X0 - t0, t0);
      h[2*p+1] = __builtin_fmaf(M1, X1 - t1, t1);
      ow[p] = pkbf(h[2*p], h[2*p+1]);
    }
    uint4 out; out.x = ow[0]; out.y = ow[1]; out.z = ow[2]; out.w = ow[3];
    *(uint4*)(hb + o) = out;
  }

  auto round = [&](const Pair& p, int t) {
    const int par = (t >> 1) & 1;
    const unsigned v0w[4] = {p.v0.x, p.v0.y, p.v0.z, p.v0.w};
    const unsigned v1w[4] = {p.v1.x, p.v1.y, p.v1.z, p.v1.w};
    const unsigned m0w[4] = {p.m0.x, p.m0.y, p.m0.z, p.m0.w};
    float vf[8], uf[8], mf0[8];
    float P0 = 0.f, P1 = 0.f, Q0 = 0.f, Q1 = 0.f;
#pragma unroll
    for (int q = 0; q < 4; ++q) {
      vf[2*q]   = blo(v0w[q]);
      vf[2*q+1] = bhi(v0w[q]);
      uf[2*q]   = blo(v1w[q]);
      uf[2*q+1] = bhi(v1w[q]);
      mf0[2*q]  = blo(m0w[q]);
      mf0[2*q+1]= bhi(m0w[q]);
      const float wa = __builtin_fmaf(-uf[2*q],   mf0[2*q],   uf[2*q]);   // v1*l0
      const float wb = __builtin_fmaf(-uf[2*q+1], mf0[2*q+1], uf[2*q+1]);
      P0 = __builtin_fmaf(vf[2*q],   h[2*q],   P0);
      P1 = __builtin_fmaf(vf[2*q+1], h[2*q+1], P1);
      Q0 = __builtin_fmaf(wa, h[2*q],   Q0);
      Q1 = __builtin_fmaf(wb, h[2*q+1], Q1);
    }
    float P = wave_sum_dpp(P0 + P1);
    float Q = wave_sum_dpp(Q0 + Q1);
    if (lane == 63) { rP[par][wave] = P; rQ[par][wave] = Q; }
    asm volatile("s_waitcnt lgkmcnt(0)\n\ts_barrier" ::: "memory");
    const float4 sp = *(const float4*)rP[par];
    const float4 sq = *(const float4*)rQ[par];
    const float a0 = (sp.x + sp.y) + (sp.z + sp.w);
    const float a1 = __builtin_fmaf(-a0, p.c.x, (sq.x + sq.y) + (sq.z + sq.w) + p.c.y);
    const unsigned xw0[4] = {p.x0.x, p.x0.y, p.x0.z, p.x0.w};
    const unsigned xw1[4] = {p.x1.x, p.x1.y, p.x1.z, p.x1.w};
    const unsigned m1w[4] = {p.m1.x, p.m1.y, p.m1.z, p.m1.w};
    unsigned ow0[4], ow1[4];
#pragma unroll
    for (int q = 0; q < 4; ++q) {
      const float A0 = blo(xw0[q]), A1 = bhi(xw0[q]);
      const float B0 = blo(xw1[q]), B1 = bhi(xw1[q]);
      const float N0 = blo(m1w[q]), N1 = bhi(m1w[q]);
      float t0 = __builtin_fmaf(vf[2*q],   -a0, h[2*q]);
      float t1 = __builtin_fmaf(vf[2*q+1], -a0, h[2*q+1]);
      t0 = __builtin_fmaf(mf0[2*q],   A0 - t0, t0);   // h_t
      t1 = __builtin_fmaf(mf0[2*q+1], A1 - t1, t1);
      ow0[q] = pkbf(t0, t1);
      const float u0 = __builtin_fmaf(uf[2*q],   -a1, t0);
      const float u1 = __builtin_fmaf(uf[2*q+1], -a1, t1);
      h[2*q]   = __builtin_fmaf(N0, B0 - u0, u0);     // h_{t+1}
      h[2*q+1] = __builtin_fmaf(N1, B1 - u1, u1);
      ow1[q] = pkbf(h[2*q], h[2*q+1]);
    }
    const size_t oo = base + (size_t)t * D_INNER;
    uint4 o0; o0.x = ow0[0]; o0.y = ow0[1]; o0.z = ow0[2]; o0.w = ow0[3];
    uint4 o1; o1.x = ow1[0]; o1.y = ow1[1]; o1.z = ow1[2]; o1.w = ow1[3];
    *(uint4*)(hb + oo) = o0;
    *(uint4*)(hb + oo + D_INNER) = o1;
  };

  // Software pipeline, depth = 2 rounds; sched_barrier(0) pins load clumps.
  Pair A = load_pair(2);
  __builtin_amdgcn_sched_barrier(0);
  Pair B = load_pair(4);
  __builtin_amdgcn_sched_barrier(0);
  for (int t = 2; t <= 2038; t += 4) {
    Pair An = load_pair(t + 4);
    __builtin_amdgcn_sched_barrier(0);
    round(A, t);
    A = An;
    Pair Bn = load_pair(t + 6);
    __builtin_amdgcn_sched_barrier(0);
    round(B, t + 2);
    B = Bn;
  }
  {
    Pair An = load_pair(2046);
    __builtin_amdgcn_sched_barrier(0);
    round(A, 2042);
    round(B, 2044);
    round(An, 2046);
  }
}

extern "C" void kernel_launch(void* const* d_in, const int* in_sizes, int n_in,
                              void* d_out, int out_size, void* d_ws, size_t ws_size,
                              hipStream_t stream)
{
  const float* x     = (const float*)d_in[0];
  const float* omega = (const float*)d_in[1];
  const float* Win   = (const float*)d_in[2];
  const float* Wl    = (const float*)d_in[3];
  const float* bl    = (const float*)d_in[4];
  const float* Wv    = (const float*)d_in[5];
  const float* bv    = (const float*)d_in[6];
  const float* Wout  = (const float*)d_in[7];
  float* out = (float*)d_out;
  (void)in_sizes; (void)n_in; (void)out_size; (void)ws_size;

  size_t off = 0;
  auto carve = [&](size_t bytes) -> void* {
    void* r = (char*)d_ws + off;
    off += (bytes + 255) & ~(size_t)255;
    return r;
  };
  u16*  x_bf    = (u16*)carve((size_t)BT * D_MODEL * 2);          // conv region base
  u16*  Win_bf  = (u16*)carve((size_t)2 * D_INNER * D_MODEL * 2);
  u16*  Wl_bf   = (u16*)carve((size_t)D_INNER * D_INNER * 2);
  u16*  Wv_bf   = (u16*)carve((size_t)D_INNER * D_INNER * 2);
  u16*  Wout_bf = (u16*)carve((size_t)D_MODEL * D_INNER * 2);
  u16*  xi_bf   = (u16*)carve((size_t)BT * D_INNER * 2);
  u16*  sz_bf   = (u16*)carve((size_t)BT * D_INNER * 2);
  u16*  v_bf    = (u16*)carve((size_t)BT * D_INNER * 2);
  u16*  gh_bf   = (u16*)carve((size_t)BT * D_INNER * 2);   // scan h, then z*h in-place
  u16*  mb      = (u16*)carve((size_t)BT * D_INNER * 2);   // 1-lam, bf16
  float* sfac   = (float*)carve((size_t)D_INNER * 4);
  f32x2* C12    = (f32x2*)carve((size_t)(BT / 2) * 8);

  // all 5 input conversions in one launch (outputs contiguous from x_bf)
  convall_kernel<<<CV_R4 / 256, 256, 0, stream>>>(x, Win, Wl, Wv, Wout, x_bf);
  sfac_kernel<<<(D_INNER + 255) / 256, 256, 0, stream>>>(omega, sfac);

  // xz = x @ Win^T  -> xi (bf16) | silu(z) (bf16)
  gemm_nt<0><<<dim3(4096 / 128, BT / 128), 256, 0, stream>>>(
      x_bf, Win_bf, BT, 4096, D_MODEL, nullptr, xi_bf, sz_bf, nullptr, nullptr, nullptr);
  // merged: mb = bf16(1-lam) | v = xi@Wv^T+bv bf16
  gemm_nt<4><<<dim3(4096 / 128, BT / 128), 256, 0, stream>>>(
      xi_bf, Wl_bf, BT, 4096, D_INNER, nullptr, v_bf, mb, bl, sfac, bv);
  // fused: v <- v*sqrt(2/(v.v)) (rounded) + C12 from rounded values
  prep_kernel<<<BT / 2 / 4, 256, 0, stream>>>(v_bf, mb, xi_bf, C12);
  // paired sequential scan (depth-2, round-4 exact) -> hb = h (bf16)
  scan2_kernel<<<NBATCH, 256, 0, stream>>>(xi_bf, v_bf, mb, C12, gh_bf);
  // gh = silu(z)*h (full chip, in-place)
  zmul_kernel<<<(BT * D_INNER / 8 + 255) / 256, 256, 0, stream>>>(gh_bf, sz_bf, BT * D_INNER / 8);
  // out = gh @ Wout^T (fp32)
  gemm_nt<3><<<dim3(D_MODEL / 128, BT / 128), 256, 0, stream>>>(
      gh_bf, Wout_bf, BT, D_MODEL, D_INNER, out, nullptr, nullptr, nullptr, nullptr, nullptr);
}